// Round 7
// baseline (290.617 us; speedup 1.0000x reference)
//
#include <hip/hip_runtime.h>
#include <hip/hip_bf16.h>

// Problem constants
#define NB 16
#define ND 512
#define NT 2048
#define TM1 2047
#define NHD 256

typedef __attribute__((ext_vector_type(8))) short bf16x8;
typedef __attribute__((ext_vector_type(4))) float f32x4;
typedef unsigned short ushort_t;
typedef unsigned int uint_t;

// ws layout (float offsets): zeroed head [0,49152), wsum, wkqT, chunk bufs.
#define G0_OFF    0ull
#define R0_OFF    32768ull                 // r0acc [16][512]
#define SX_OFF    40960ull                 // sxacc [16][512]
#define WSUM_OFF  49152ull
#define WKQT_OFF  49408ull                 // 512*512 bf16 = 131072 floats
#define CHUNK_OFF 180480ull
#define BATCH_US  (2048ull * 512ull)       // ushorts per batch (xst), 2 MB
#define BATCH_FLOATS 524288ull             // xst floats per batch

__device__ __forceinline__ ushort_t f2bf(float x) {
    union { float f; uint_t u; } v; v.f = x;
    uint_t r = v.u + 0x7FFFu + ((v.u >> 16) & 1u);  // round-to-nearest-even
    return (ushort_t)(r >> 16);
}
__device__ __forceinline__ float bf2f(uint_t u) {
    union { uint_t u; float f; } v; v.u = u << 16;
    return v.f;
}

// Async global->LDS DMA, 16 B/lane, 1024 B/wave-instruction.
__device__ __forceinline__ void async_copy16(const ushort_t* g, ushort_t* l) {
    __builtin_amdgcn_global_load_lds(
        (const __attribute__((address_space(1))) void*)g,
        (__attribute__((address_space(3))) void*)l, 16, 0, 0);
}

#define FENCE() asm volatile("" ::: "memory")
#define BARRIER() do { FENCE(); __builtin_amdgcn_s_barrier(); FENCE(); } while (0)
#define WAITVM0() asm volatile("s_waitcnt vmcnt(0)" ::: "memory")

// --- xst[c][t][d] = bf16(xs[b0+c][d][t]);  + (cc==0,b0==0) prep work -----
// Prep folded in: wkqT = bf16(wkq^T), zero scratch head, wsum = sum(wlast).
__global__ __launch_bounds__(256) void k_cvt_xst(const float* __restrict__ xs,
                                                 ushort_t* __restrict__ xst, int b0,
                                                 const float* __restrict__ wkq,
                                                 ushort_t* __restrict__ wkqT,
                                                 const float* __restrict__ wlast,
                                                 float* __restrict__ wsum,
                                                 float* __restrict__ zbase) {
    __shared__ float tile[64][257];
    const int t0 = blockIdx.x * 256, d0 = blockIdx.y * 64;
    const int cc = blockIdx.z;
    const float* xb = xs + (size_t)(b0 + cc) * ND * NT;
    ushort_t* xo = xst + (size_t)cc * BATCH_US;
    const int wave = threadIdx.x >> 6, lane = threadIdx.x & 63;
    #pragma unroll
    for (int i = 0; i < 16; ++i) {
        const int row = wave * 16 + i;
        *(float4*)&tile[row][lane * 4] =
            *(const float4*)&xb[(size_t)(d0 + row) * NT + t0 + lane * 4];
    }
    __syncthreads();
    const int c8 = (threadIdx.x & 7) * 8;
    #pragma unroll
    for (int i = 0; i < 8; ++i) {
        const int t = i * 32 + (threadIdx.x >> 3);
        uint_t w[4];
        #pragma unroll
        for (int p = 0; p < 4; ++p)
            w[p] = (uint_t)f2bf(tile[c8 + 2 * p][t]) |
                   ((uint_t)f2bf(tile[c8 + 2 * p + 1][t]) << 16);
        *(uint4*)&xo[(size_t)(t0 + t) * ND + d0 + c8] = *(uint4*)w;
    }
    // ---- prep (once, on the cc==0 plane of the first chunk) ----
    if (cc == 0 && b0 == 0) {
        __shared__ float ptile[32][33];
        const int bid = blockIdx.y * 8 + blockIdx.x;   // 0..63
        const int c = threadIdx.x & 31, r = threadIdx.x >> 5;  // r in 0..7
        #pragma unroll 1
        for (int q = 0; q < 4; ++q) {
            const int job = bid * 4 + q;               // 0..255
            const int j0 = (job & 15) * 32, dd0 = (job >> 4) * 32;
            __syncthreads();
            #pragma unroll
            for (int i = 0; i < 4; ++i)
                ptile[r + i * 8][c] = wkq[(size_t)(dd0 + r + i * 8) * ND + j0 + c];
            __syncthreads();
            #pragma unroll
            for (int i = 0; i < 4; ++i)
                wkqT[(size_t)(j0 + r + i * 8) * ND + dd0 + c] = f2bf(ptile[c][r + i * 8]);
        }
        // zero head scratch: 49152 floats = 64 blocks x 768
        #pragma unroll
        for (int k = 0; k < 3; ++k)
            zbase[bid * 768 + k * 256 + threadIdx.x] = 0.f;
        if (bid == 0) {
            __shared__ float red[256];
            float s = 0.f;
            for (int t = threadIdx.x; t < NT; t += 256) s += wlast[t];
            red[threadIdx.x] = s;
            __syncthreads();
            for (int off = 128; off > 0; off >>= 1) {
                if (threadIdx.x < off) red[threadIdx.x] += red[threadIdx.x + off];
                __syncthreads();
            }
            if (threadIdx.x == 0) *wsum = red[0];
        }
    }
}

// --- k_fused: qd + attention for one (batch, s-tile of 128), all t -------
// Phase 1: qd[s][j] = sgn_j * sum_d xst[s][d]*wkqT[j][d]  (into LDS panel)
// Phase 2: g0[b,s] = sum_t sigmoid(sum_j qd[s,j]*xst[t,j]) * w[t]
// Panel: 8 k-tile bufs [128][64] bf16, XOR-swizzled (elem (row,c) at chunk
// (c>>3)^(row&7)).  Holds xst s-tile in phase 1, qd in phase 2 (read-only
// in both compute loops).  B operands stream global->registers wave-private
// -> ZERO barriers in both hot loops (de-lockstep: rounds 1-6 all showed
// ~70% no-issue stall with barrier-phased schedules, invariant to phase
// count / buffering / blocks-per-CU).
__global__ __launch_bounds__(512, 2) void k_fused(const ushort_t* __restrict__ xst,
                                                  const ushort_t* __restrict__ wkqT,
                                                  const float* __restrict__ wlast,
                                                  float* __restrict__ g0, int b0) {
    __shared__ __align__(16) ushort_t panel[8][8192];   // 8 x (128 rows x 64)
    __shared__ float lds_g[128];
    // XCD swizzle (bijective, nwg = 16*cb, cb even): group s-tiles of the
    // same batch on one XCD so xst/wkqT panels stay L2-hot.
    const int lin = blockIdx.x + gridDim.x * blockIdx.y;
    const int nwg8 = (gridDim.x * gridDim.y) >> 3;
    const int logical = (lin & 7) * nwg8 + (lin >> 3);
    const int st = logical & 15;
    const int cc = logical >> 4;
    const int s0 = st * 128;
    const int b = b0 + cc;

    const int tid = threadIdx.x;
    const int wave = tid >> 6, lane = tid & 63;
    const int l15 = lane & 15, quad = lane >> 4;
    const ushort_t* xb = xst + (size_t)cc * BATCH_US;

    // ---- prologue: stage xst s-tile (128x512) into 8 swizzled bufs ----
    const int lrow = lane >> 3;
    const size_t lsrc = (size_t)lrow * ND + (size_t)(((lane & 7) ^ lrow) << 3);
    {
        const ushort_t* Ag = xb + (size_t)s0 * ND;
        #pragma unroll
        for (int kt = 0; kt < 8; ++kt) {
            const ushort_t* gp = Ag + (size_t)(wave * 16) * ND + kt * 64 + lsrc;
            async_copy16(gp, &panel[kt][wave * 1024]);
            async_copy16(gp + (size_t)8 * ND, &panel[kt][wave * 1024 + 512]);
        }
    }
    if (tid < 128) lds_g[tid] = 0.f;
    WAITVM0();
    BARRIER();

    // ---- phase 1: wave owns j-cols wave*64..+64 (B = wkqT, wave-private)
    {
        f32x4 a1[8][4];
        #pragma unroll
        for (int mi = 0; mi < 8; ++mi)
            #pragma unroll
            for (int nj = 0; nj < 4; ++nj) a1[mi][nj] = (f32x4){0.f, 0.f, 0.f, 0.f};
        const ushort_t* Wg = wkqT + (size_t)(wave * 64) * ND;
        #pragma unroll 1
        for (int kt = 0; kt < 8; ++kt) {
            bf16x8 bw[4][2];
            #pragma unroll
            for (int nj = 0; nj < 4; ++nj)
                #pragma unroll
                for (int kc = 0; kc < 2; ++kc)
                    bw[nj][kc] = *(const bf16x8*)&Wg[(size_t)(nj * 16 + l15) * ND +
                                                     kt * 64 + ((kc * 4 + quad) << 3)];
            __builtin_amdgcn_s_setprio(1);
            #pragma unroll
            for (int mi = 0; mi < 8; ++mi) {
                const int row = mi * 16 + l15;
                const bf16x8 af0 = *(const bf16x8*)&panel[kt][row * 64 + ((quad ^ (row & 7)) << 3)];
                const bf16x8 af1 = *(const bf16x8*)&panel[kt][row * 64 + (((4 + quad) ^ (row & 7)) << 3)];
                #pragma unroll
                for (int nj = 0; nj < 4; ++nj) {
                    a1[mi][nj] = __builtin_amdgcn_mfma_f32_16x16x32_bf16(af0, bw[nj][0], a1[mi][nj], 0, 0, 0);
                    a1[mi][nj] = __builtin_amdgcn_mfma_f32_16x16x32_bf16(af1, bw[nj][1], a1[mi][nj], 0, 0, 0);
                }
            }
            __builtin_amdgcn_s_setprio(0);
        }
        BARRIER();   // all waves done reading xst panel
        // scatter qd (bf16, signed) into panel buf[wave] (j>>6 == wave)
        const float sgn = (wave < 4) ? 1.f : -1.f;
        #pragma unroll
        for (int mi = 0; mi < 8; ++mi)
            #pragma unroll
            for (int nj = 0; nj < 4; ++nj)
                #pragma unroll
                for (int r = 0; r < 4; ++r) {
                    const int srow = mi * 16 + quad * 4 + r;
                    const int c = nj * 16 + l15;
                    panel[wave][srow * 64 + ((((c >> 3) ^ (srow & 7)) << 3) | (c & 7))] =
                        f2bf(sgn * a1[mi][nj][r]);
                }
    }
    BARRIER();

    // ---- phase 2: Delta + sigmoid over 8 t-tiles of 256, K = 512 -------
    const int wm = wave >> 2, wn = wave & 3;       // 2 (M=64s) x 4 (N=64t)
    f32x4 acc[4][4];
    #pragma unroll
    for (int mi = 0; mi < 4; ++mi)
        #pragma unroll
        for (int nj = 0; nj < 4; ++nj) acc[mi][nj] = (f32x4){0.f, 0.f, 0.f, 0.f};
    bf16x8 bx0[4][2], bx1[4][2];

// Load B fragments for step s_ (kt = s_&7, tt = s_>>3) into dst_ (regs).
#define LOADB(dst_, s_) do {                                                  \
        const int kt_ = (s_) & 7, tt_ = (s_) >> 3;                            \
        const ushort_t* bb_ = xb + (size_t)(tt_ * 256 + wn * 64) * ND + kt_ * 64; \
        _Pragma("unroll")                                                     \
        for (int nj = 0; nj < 4; ++nj)                                        \
            _Pragma("unroll")                                                 \
            for (int kc = 0; kc < 2; ++kc)                                    \
                dst_[nj][kc] = *(const bf16x8*)&bb_[(size_t)(nj * 16 + l15) * ND + \
                                                    ((kc * 4 + quad) << 3)];  \
    } while (0)
// 32 MFMA for step s_: A from panel[kt], B from bx_.
#define PV(bx_, s_) do {                                                      \
        const int kt_ = (s_) & 7;                                             \
        __builtin_amdgcn_s_setprio(1);                                        \
        _Pragma("unroll")                                                     \
        for (int mi = 0; mi < 4; ++mi) {                                      \
            const int row_ = wm * 64 + mi * 16 + l15;                         \
            const bf16x8 af0_ = *(const bf16x8*)&panel[kt_][row_ * 64 + ((quad ^ (row_ & 7)) << 3)]; \
            const bf16x8 af1_ = *(const bf16x8*)&panel[kt_][row_ * 64 + (((4 + quad) ^ (row_ & 7)) << 3)]; \
            _Pragma("unroll")                                                 \
            for (int nj = 0; nj < 4; ++nj) {                                  \
                acc[mi][nj] = __builtin_amdgcn_mfma_f32_16x16x32_bf16(af0_, bx_[nj][0], acc[mi][nj], 0, 0, 0); \
                acc[mi][nj] = __builtin_amdgcn_mfma_f32_16x16x32_bf16(af1_, bx_[nj][1], acc[mi][nj], 0, 0, 0); \
            }                                                                 \
        }                                                                     \
        __builtin_amdgcn_s_setprio(0);                                        \
    } while (0)
// Sigmoid-weighted dump of acc for t-tile tt_ into lds_g (atomic, no sync).
#define DUMP(tt_) do {                                                        \
        float wt_[4];                                                         \
        _Pragma("unroll")                                                     \
        for (int nj = 0; nj < 4; ++nj)                                        \
            wt_[nj] = wlast[(tt_) * 256 + wn * 64 + nj * 16 + l15];           \
        _Pragma("unroll")                                                     \
        for (int mi = 0; mi < 4; ++mi)                                        \
            _Pragma("unroll")                                                 \
            for (int r = 0; r < 4; ++r) {                                     \
                float v_ = 0.f;                                               \
                _Pragma("unroll")                                             \
                for (int nj = 0; nj < 4; ++nj) {                              \
                    const float e_ = __expf(-acc[mi][nj][r]);                 \
                    v_ = fmaf(__builtin_amdgcn_rcpf(1.f + e_), wt_[nj], v_);  \
                }                                                             \
                v_ += __shfl_xor(v_, 1);                                      \
                v_ += __shfl_xor(v_, 2);                                      \
                v_ += __shfl_xor(v_, 4);                                      \
                v_ += __shfl_xor(v_, 8);                                      \
                if (l15 == 0)                                                 \
                    atomicAdd(&lds_g[wm * 64 + mi * 16 + quad * 4 + r], v_);  \
            }                                                                 \
        _Pragma("unroll")                                                     \
        for (int mi = 0; mi < 4; ++mi)                                        \
            _Pragma("unroll")                                                 \
            for (int nj = 0; nj < 4; ++nj) acc[mi][nj] = (f32x4){0.f, 0.f, 0.f, 0.f}; \
    } while (0)

    LOADB(bx0, 0);
    #pragma unroll 1
    for (int jp = 0; jp < 32; ++jp) {
        const int sA = 2 * jp, sB = 2 * jp + 1;
        LOADB(bx1, sB);
        PV(bx0, sA);
        if (jp < 31) LOADB(bx0, sB + 1);
        PV(bx1, sB);
        if ((sB & 7) == 7) DUMP(sB >> 3);
    }
#undef LOADB
#undef PV
#undef DUMP

    __syncthreads();
    if (tid < 128) {
        const int srow = s0 + tid;
        if (srow < TM1) g0[b * TM1 + srow] = lds_g[tid];   // exclusive owner
    }
}

// --- r partials from bf16 xst (coalesced d-major) ------------------------
__global__ __launch_bounds__(256) void k_r(const ushort_t* __restrict__ xst,
                                           const float* __restrict__ g0,
                                           float* __restrict__ r0acc,
                                           float* __restrict__ sxacc, int b0) {
    const int sc = blockIdx.x;            // s-chunk of 64
    const int cc = blockIdx.y;
    const int b = b0 + cc;
    const ushort_t* xa = xst + (size_t)cc * BATCH_US;
    const float* g = g0 + b * TM1;
    const int d2 = threadIdx.x;           // owns d = 2*d2, 2*d2+1
    float a00 = 0.f, a01 = 0.f, a10 = 0.f, a11 = 0.f;
    const int send = (sc == 31) ? 63 : 64;   // exclude s = 2047
    for (int si = 0; si < send; ++si) {
        const int s = sc * 64 + si;
        const float gv = g[s];
        const uint_t pk = *(const uint_t*)&xa[(size_t)s * ND + d2 * 2];
        const float x0 = bf2f(pk & 0xFFFFu);
        const float x1 = bf2f(pk >> 16);
        a00 = fmaf(x0, gv, a00); a01 = fmaf(x1, gv, a01);
        a10 += x0; a11 += x1;
    }
    atomicAdd(&r0acc[b * ND + d2 * 2], a00);
    atomicAdd(&r0acc[b * ND + d2 * 2 + 1], a01);
    atomicAdd(&sxacc[b * ND + d2 * 2], a10);
    atomicAdd(&sxacc[b * ND + d2 * 2 + 1], a11);
}

// --- out[b,i] = sum_d W_PV[i,d] * r[b, i/256, d]  (fp32 out) -------------
__global__ __launch_bounds__(256) void k_out(const float* __restrict__ wpv,
                                             const float* __restrict__ r0acc,
                                             const float* __restrict__ sxacc,
                                             const float* __restrict__ wsum,
                                             float* __restrict__ out) {
    const int b = blockIdx.x;
    const int i0 = blockIdx.y * 256;
    __shared__ float rs[1024];
    const float wsv = *wsum;
    for (int i = threadIdx.x; i < ND; i += 256) {
        const float r0 = r0acc[b * ND + i];
        const float sx = sxacc[b * ND + i];
        rs[i] = r0;                        // head 0
        rs[ND + i] = fmaf(wsv, sx, -r0);   // head 1
    }
    __syncthreads();
    const int i = i0 + threadIdx.x;
    const float* wrow = wpv + (size_t)i * ND;
    const float* rh = rs + (i >> 8) * ND;
    float acc = 0.f;
    for (int dd = 0; dd < ND; dd += 4) {
        const float4 wv = *(const float4*)(wrow + dd);
        acc += wv.x * rh[dd] + wv.y * rh[dd + 1] + wv.z * rh[dd + 2] + wv.w * rh[dd + 3];
    }
    out[b * ND + i] = acc;
}

extern "C" void kernel_launch(void* const* d_in, const int* in_sizes, int n_in,
                              void* d_out, int out_size, void* d_ws, size_t ws_size,
                              hipStream_t stream) {
    (void)in_sizes; (void)n_in; (void)out_size;
    const float* xs   = (const float*)d_in[0];
    const float* wkq  = (const float*)d_in[1];
    const float* wpv  = (const float*)d_in[2];
    const float* wout = (const float*)d_in[3];
    const float* wlast = wout + (size_t)(NT - 1) * NT;  // W_out[-1]

    float* ws    = (float*)d_ws;
    float* g0    = ws + G0_OFF;
    float* r0acc = ws + R0_OFF;
    float* sxacc = ws + SX_OFF;
    float* wsum  = ws + WSUM_OFF;
    ushort_t* wkqT = (ushort_t*)(ws + WKQT_OFF);

    // Chunk batches: per batch needs 2 MB xst of ws (qdb eliminated).
    const size_t ws_floats = ws_size / 4;
    size_t avail = (ws_floats > CHUNK_OFF) ? (ws_floats - CHUNK_OFF) : 0;
    int C = (int)(avail / BATCH_FLOATS);
    if (C > NB) C = NB;
    if (C < 1) C = 1;
    if (C > 1 && (C & 1)) C -= 1;          // keep nwg multiple of 8
    ushort_t* xst = (ushort_t*)(ws + CHUNK_OFF);

    for (int b0 = 0; b0 < NB; b0 += C) {
        const int cb = (NB - b0 < C) ? (NB - b0) : C;
        k_cvt_xst<<<dim3(8, 8, cb), 256, 0, stream>>>(xs, xst, b0,
                                                      wkq, wkqT, wlast, wsum, ws);
        k_fused  <<<dim3(16, cb),  512, 0, stream>>>(xst, wkqT, wlast, g0, b0);
        k_r      <<<dim3(32, cb),  256, 0, stream>>>(xst, g0, r0acc, sxacc, b0);
    }
    k_out<<<dim3(NB, 2), 256, 0, stream>>>(wpv, r0acc, sxacc, wsum, (float*)d_out);
}

// Round 8
// 261.042 us; speedup vs baseline: 1.1133x; 1.1133x over previous
//
#include <hip/hip_runtime.h>
#include <hip/hip_bf16.h>

// Problem constants
#define NB 16
#define ND 512
#define NT 2048
#define TM1 2047
#define NHD 256

typedef __attribute__((ext_vector_type(8))) short bf16x8;
typedef __attribute__((ext_vector_type(4))) float f32x4;
typedef unsigned short ushort_t;
typedef unsigned int uint_t;

// ws layout (float offsets): zeroed head [0,49152), wsum, wkqT, chunk bufs.
#define G0_OFF    0ull
#define R0_OFF    32768ull                 // r0acc [16][512]
#define SX_OFF    40960ull                 // sxacc [16][512]
#define WSUM_OFF  49152ull
#define WKQT_OFF  49408ull                 // 512*512 bf16 = 131072 floats
#define CHUNK_OFF 180480ull
#define BATCH_US  (2048ull * 512ull)       // ushorts per batch per array (2 MB)
#define BATCH_FLOATS (2ull * 524288ull)    // qdb + xst floats per batch (4 MB)

__device__ __forceinline__ ushort_t f2bf(float x) {
    union { float f; uint_t u; } v; v.f = x;
    uint_t r = v.u + 0x7FFFu + ((v.u >> 16) & 1u);  // round-to-nearest-even
    return (ushort_t)(r >> 16);
}
__device__ __forceinline__ float bf2f(uint_t u) {
    union { uint_t u; float f; } v; v.u = u << 16;
    return v.f;
}

// Async global->LDS DMA, 16 B/lane, 1024 B/wave-instruction.
__device__ __forceinline__ void async_copy16(const ushort_t* g, ushort_t* l) {
    __builtin_amdgcn_global_load_lds(
        (const __attribute__((address_space(1))) void*)g,
        (__attribute__((address_space(3))) void*)l, 16, 0, 0);
}

#define FENCE() asm volatile("" ::: "memory")
#define BARRIER() do { FENCE(); __builtin_amdgcn_s_barrier(); FENCE(); } while (0)
#define WAITVM4() asm volatile("s_waitcnt vmcnt(4)" ::: "memory")
#define WAITVM0() asm volatile("s_waitcnt vmcnt(0)" ::: "memory")

// --- xst[c][t][d] = bf16(xs[b0+c][d][t]);  + (cc==0,b0==0) prep work -----
// Prep folded in: wkqT = bf16(wkq^T), zero scratch head, wsum = sum(wlast).
__global__ __launch_bounds__(256) void k_cvt_xst(const float* __restrict__ xs,
                                                 ushort_t* __restrict__ xst, int b0,
                                                 const float* __restrict__ wkq,
                                                 ushort_t* __restrict__ wkqT,
                                                 const float* __restrict__ wlast,
                                                 float* __restrict__ wsum,
                                                 float* __restrict__ zbase) {
    __shared__ float tile[64][257];
    const int t0 = blockIdx.x * 256, d0 = blockIdx.y * 64;
    const int cc = blockIdx.z;
    const float* xb = xs + (size_t)(b0 + cc) * ND * NT;
    ushort_t* xo = xst + (size_t)cc * BATCH_US;
    const int wave = threadIdx.x >> 6, lane = threadIdx.x & 63;
    #pragma unroll
    for (int i = 0; i < 16; ++i) {
        const int row = wave * 16 + i;
        *(float4*)&tile[row][lane * 4] =
            *(const float4*)&xb[(size_t)(d0 + row) * NT + t0 + lane * 4];
    }
    __syncthreads();
    const int c8 = (threadIdx.x & 7) * 8;
    #pragma unroll
    for (int i = 0; i < 8; ++i) {
        const int t = i * 32 + (threadIdx.x >> 3);
        uint_t w[4];
        #pragma unroll
        for (int p = 0; p < 4; ++p)
            w[p] = (uint_t)f2bf(tile[c8 + 2 * p][t]) |
                   ((uint_t)f2bf(tile[c8 + 2 * p + 1][t]) << 16);
        *(uint4*)&xo[(size_t)(t0 + t) * ND + d0 + c8] = *(uint4*)w;
    }
    // ---- prep (once, on the cc==0 plane of the first chunk) ----
    if (cc == 0 && b0 == 0) {
        __shared__ float ptile[32][33];
        const int bid = blockIdx.y * 8 + blockIdx.x;   // 0..63
        const int c = threadIdx.x & 31, r = threadIdx.x >> 5;  // r in 0..7
        #pragma unroll 1
        for (int q = 0; q < 4; ++q) {
            const int job = bid * 4 + q;               // 0..255
            const int j0 = (job & 15) * 32, dd0 = (job >> 4) * 32;
            __syncthreads();
            #pragma unroll
            for (int i = 0; i < 4; ++i)
                ptile[r + i * 8][c] = wkq[(size_t)(dd0 + r + i * 8) * ND + j0 + c];
            __syncthreads();
            #pragma unroll
            for (int i = 0; i < 4; ++i)
                wkqT[(size_t)(j0 + r + i * 8) * ND + dd0 + c] = f2bf(ptile[c][r + i * 8]);
        }
        // zero head scratch: 49152 floats = 64 blocks x 768
        #pragma unroll
        for (int k = 0; k < 3; ++k)
            zbase[bid * 768 + k * 256 + threadIdx.x] = 0.f;
        if (bid == 0) {
            __shared__ float red[256];
            float s = 0.f;
            for (int t = threadIdx.x; t < NT; t += 256) s += wlast[t];
            red[threadIdx.x] = s;
            __syncthreads();
            for (int off = 128; off > 0; off >>= 1) {
                if (threadIdx.x < off) red[threadIdx.x] += red[threadIdx.x + off];
                __syncthreads();
            }
            if (threadIdx.x == 0) *wsum = red[0];
        }
    }
}

// === helpers for the 256x256 BK=64 8-phase core (k_qd, r2-validated) =====
__device__ __forceinline__ void ld_frag4(bf16x8 (&dst)[4][2], const ushort_t* buf,
                                         int rbase, int l15, int quad, int swz) {
    #pragma unroll
    for (int i = 0; i < 4; ++i)
        #pragma unroll
        for (int kc = 0; kc < 2; ++kc)
            dst[i][kc] = *(const bf16x8*)&buf[(rbase + i * 16 + l15) * 64 + (((kc * 4 + quad) ^ swz) << 3)];
}
__device__ __forceinline__ void ld_frag2(bf16x8 (&dst)[2][2], const ushort_t* buf,
                                         int rbase, int l15, int quad, int swz) {
    #pragma unroll
    for (int i = 0; i < 2; ++i)
        #pragma unroll
        for (int kc = 0; kc < 2; ++kc)
            dst[i][kc] = *(const bf16x8*)&buf[(rbase + i * 16 + l15) * 64 + (((kc * 4 + quad) ^ swz) << 3)];
}
__device__ __forceinline__ void mfma8(f32x4 (&acc)[8][4], const bf16x8 (&a)[4][2],
                                      const bf16x8 (&bb)[2][2], int mbase, int nbase) {
    __builtin_amdgcn_s_setprio(1);
    #pragma unroll
    for (int kc = 0; kc < 2; ++kc)
        #pragma unroll
        for (int mi = 0; mi < 4; ++mi)
            #pragma unroll
            for (int nj = 0; nj < 2; ++nj)
                acc[mbase + mi][nbase + nj] = __builtin_amdgcn_mfma_f32_16x16x32_bf16(
                    a[mi][kc], bb[nj][kc], acc[mbase + mi][nbase + nj], 0, 0, 0);
    __builtin_amdgcn_s_setprio(0);
}

__device__ __forceinline__ void gemm8ph(const ushort_t* __restrict__ Ag,
                                        const ushort_t* __restrict__ Bg,
                                        ushort_t* __restrict__ smA0, ushort_t* __restrict__ smA1,
                                        ushort_t* __restrict__ smB0, ushort_t* __restrict__ smB1,
                                        f32x4 (&acc)[8][4]) {
    const int tid = threadIdx.x;
    const int wave = tid >> 6, lane = tid & 63;
    const int l15 = lane & 15, quad = lane >> 4;
    const int wm = wave >> 2;                      // 2 (M) x 4 (N) waves
    const int swz = l15 & 7;
    const int lrow = lane >> 3;
    const size_t lsrc = (size_t)lrow * ND + (size_t)(((lane & 7) ^ lrow) << 3);
    ushort_t* smA[2] = {smA0, smA1};
    ushort_t* smB[2] = {smB0, smB1};

#define STAGE(gb_, buf_, kt_, h_) do {                                        \
        const ushort_t* g_ = (gb_) + (size_t)((h_) * 128 + wave * 8) * ND +   \
                             (kt_) * 64 + lsrc;                               \
        ushort_t* l_ = (buf_) + (h_) * 8192 + wave * 512;                     \
        async_copy16(g_, l_);                                                 \
        async_copy16(g_ + (size_t)64 * ND, l_ + 4096);                        \
    } while (0)

    bf16x8 a[4][2], br[2][2][2];

    STAGE(Bg, smB[0], 0, 0); STAGE(Bg, smB[0], 0, 1);
    STAGE(Ag, smA[0], 0, 0); STAGE(Ag, smA[0], 0, 1);
    STAGE(Bg, smB[1], 1, 0); STAGE(Bg, smB[1], 1, 1);
    WAITVM4();
    BARRIER();

    #pragma unroll
    for (int j = 0; j < 4; ++j) {
        const int kO = 2 * j + 1;
        ld_frag4(a, smA[0], wm * 128, l15, quad, swz);
        ld_frag2(br[0], smB[0], (wave & 3) * 64, l15, quad, swz);
        STAGE(Ag, smA[1], kO, 0);
        BARRIER();
        mfma8(acc, a, br[0], 0, 0);
        BARRIER();
        ld_frag2(br[1], smB[0], (wave & 3) * 64 + 32, l15, quad, swz);
        STAGE(Ag, smA[1], kO, 1);
        BARRIER();
        mfma8(acc, a, br[1], 0, 2);
        BARRIER();
        ld_frag4(a, smA[0], wm * 128 + 64, l15, quad, swz);
        if (j < 3) STAGE(Bg, smB[0], 2 * j + 2, 0);
        BARRIER();
        mfma8(acc, a, br[0], 4, 0);
        BARRIER();
        if (j < 3) STAGE(Bg, smB[0], 2 * j + 2, 1);
        BARRIER();
        mfma8(acc, a, br[1], 4, 2);
        if (j < 3) { WAITVM4(); } else { WAITVM0(); }
        BARRIER();
        ld_frag4(a, smA[1], wm * 128, l15, quad, swz);
        ld_frag2(br[0], smB[1], (wave & 3) * 64, l15, quad, swz);
        if (j < 3) STAGE(Ag, smA[0], 2 * j + 2, 0);
        BARRIER();
        mfma8(acc, a, br[0], 0, 0);
        BARRIER();
        ld_frag2(br[1], smB[1], (wave & 3) * 64 + 32, l15, quad, swz);
        if (j < 3) STAGE(Ag, smA[0], 2 * j + 2, 1);
        BARRIER();
        mfma8(acc, a, br[1], 0, 2);
        BARRIER();
        ld_frag4(a, smA[1], wm * 128 + 64, l15, quad, swz);
        if (j < 3) STAGE(Bg, smB[1], kO + 2, 0);
        BARRIER();
        mfma8(acc, a, br[0], 4, 0);
        BARRIER();
        if (j < 3) STAGE(Bg, smB[1], kO + 2, 1);
        BARRIER();
        mfma8(acc, a, br[1], 4, 2);
        if (j < 3) WAITVM4();
        BARRIER();
    }
#undef STAGE
}

// --- qdb[c][s][j] = bf16( sign_j * sum_d xst[c][s][d] * wkqT[j][d] ) -----
__global__ __launch_bounds__(512, 2) void k_qd(const ushort_t* __restrict__ xst,
                                               const ushort_t* __restrict__ wkqT,
                                               ushort_t* __restrict__ qdb) {
    __shared__ __align__(16) ushort_t smA[2][16384];
    __shared__ __align__(16) ushort_t smB[2][16384];
    const int lin = blockIdx.x + gridDim.x * (blockIdx.y + gridDim.y * blockIdx.z);
    const int nwg8 = (gridDim.x * gridDim.y * gridDim.z) >> 3;
    const int logical = (lin & 7) * nwg8 + (lin >> 3);
    const int jt = logical & 1;
    const int st = (logical >> 1) & 7;
    const int cc = logical >> 4;
    const int j0 = jt * 256, s0 = st * 256;

    const ushort_t* Ag = xst + (size_t)cc * BATCH_US + (size_t)s0 * ND;
    const ushort_t* Bg = wkqT + (size_t)j0 * ND;
    ushort_t* qo = qdb + (size_t)cc * BATCH_US;

    f32x4 acc[8][4];
    #pragma unroll
    for (int mi = 0; mi < 8; ++mi)
        #pragma unroll
        for (int nj = 0; nj < 4; ++nj) acc[mi][nj] = (f32x4){0.f, 0.f, 0.f, 0.f};

    gemm8ph(Ag, Bg, smA[0], smA[1], smB[0], smB[1], acc);

    const int tid = threadIdx.x;
    const int wave = tid >> 6, lane = tid & 63;
    const int l15 = lane & 15, quad = lane >> 4;
    const int wm = wave >> 2, wn = wave & 3;
    const float sgn = (j0 == 0) ? 1.f : -1.f;      // j>=256 is head-1 (negated)
    #pragma unroll
    for (int mi = 0; mi < 8; ++mi) {
        const int srow = s0 + wm * 128 + mi * 16 + quad * 4;
        #pragma unroll
        for (int nj = 0; nj < 4; ++nj) {
            const int jcol = j0 + wn * 64 + nj * 16 + l15;
            #pragma unroll
            for (int r = 0; r < 4; ++r)
                qo[(size_t)(srow + r) * ND + jcol] = f2bf(sgn * acc[mi][nj][r]);
        }
    }
}

// --- k_attn: m97-exact single-buffered 128x128 loop at 4 blocks/CU -------
// g0[b,s] += sum_t sigmoid(Delta[b,s,t]) * w[t];  Delta = qdb[s,:].xst[t,:]
// 256 thr / 4 waves (2Mx2N, 64x64/wave, acc=64 regs); LDS 32.5 KiB single
// A+B buffer -> 4 co-resident blocks/CU = 4 independent barrier domains:
// one block's vmcnt(0)-drain / LDS-burst / MFMA-burst interleaves with 3
// phase-shifted neighbors (m114 cross-block overlap -- the mechanism all
// prior rounds lacked: r0 2.4blk, r4 conflicts, r6 2blk, r7 1blk).
// Persistent over a t-quarter: 32 iters (8 kt x 4 tt), one prologue.
// __launch_bounds__(256,4) caps VGPR at 128 (acc 64 + frags ~110 total).
__global__ __launch_bounds__(256, 4) void k_attn(const ushort_t* __restrict__ qdb,
                                                 const ushort_t* __restrict__ xst,
                                                 const float* __restrict__ wlast,
                                                 float* __restrict__ g0, int b0) {
    __shared__ __align__(16) ushort_t smA[8192];   // 128 x 64
    __shared__ __align__(16) ushort_t smB[8192];   // 128 x 64
    __shared__ float lds_g[128];
    // XCD swizzle (bijective: nwg = 64*cb, %8==0): contiguous logicals on
    // one XCD share the same cc (B panel 2 MB + A panel 2 MB L2-resident).
    const int lin = blockIdx.x + gridDim.x * (blockIdx.y + gridDim.y * blockIdx.z);
    const int nwg8 = (gridDim.x * gridDim.y * gridDim.z) >> 3;
    const int logical = (lin & 7) * nwg8 + (lin >> 3);
    const int st = logical & 15;
    const int tq = (logical >> 4) & 3;
    const int cc = logical >> 6;
    const int s0 = st * 128;
    const int b = b0 + cc;

    const int tid = threadIdx.x;
    const int wave = tid >> 6, lane = tid & 63;
    const int l15 = lane & 15, quad = lane >> 4;
    const int wm = wave >> 1, wn = wave & 1;       // 2 (M) x 2 (N)
    const int swz = l15 & 7;
    const int lrow = lane >> 3;
    const size_t lsrc = (size_t)lrow * ND + (size_t)(((lane & 7) ^ lrow) << 3);
    const ushort_t* Ag = qdb + (size_t)cc * BATCH_US + (size_t)s0 * ND;
    const ushort_t* Bg = xst + (size_t)cc * BATCH_US + (size_t)(tq * 512) * ND;

// Stage a 128x64 tile (16 KB): 4 gload_lds/wave (8 rows each), linear LDS
// dest + pre-swizzled global source (validated pattern).
#define STAGEA(kt_) do {                                                      \
        const size_t ko_ = (size_t)(kt_) * 64;                                \
        _Pragma("unroll")                                                     \
        for (int n_ = 0; n_ < 4; ++n_) {                                      \
            const int rb_ = wave * 32 + n_ * 8;                               \
            async_copy16(Ag + (size_t)rb_ * ND + ko_ + lsrc, smA + rb_ * 64); \
        }                                                                     \
    } while (0)
#define STAGEB(kt_, tt_) do {                                                 \
        const size_t ko_ = (size_t)(kt_) * 64;                                \
        const size_t ro_ = (size_t)(tt_) * 128;                               \
        _Pragma("unroll")                                                     \
        for (int n_ = 0; n_ < 4; ++n_) {                                      \
            const int rb_ = wave * 32 + n_ * 8;                               \
            async_copy16(Bg + (ro_ + rb_) * ND + ko_ + lsrc, smB + rb_ * 64); \
        }                                                                     \
    } while (0)
// 32 MFMA/wave: full 128x128x64 K-tile from smA/smB (r6-validated math).
#define COMPUTE() do {                                                        \
        _Pragma("unroll")                                                     \
        for (int kc = 0; kc < 2; ++kc) {                                      \
            bf16x8 af_[4], bf_[4];                                            \
            _Pragma("unroll")                                                 \
            for (int mi = 0; mi < 4; ++mi)                                    \
                af_[mi] = *(const bf16x8*)&smA[(wm * 64 + mi * 16 + l15) * 64 \
                          + (((kc * 4 + quad) ^ swz) << 3)];                  \
            _Pragma("unroll")                                                 \
            for (int nj = 0; nj < 4; ++nj)                                    \
                bf_[nj] = *(const bf16x8*)&smB[(wn * 64 + nj * 16 + l15) * 64 \
                          + (((kc * 4 + quad) ^ swz) << 3)];                  \
            __builtin_amdgcn_s_setprio(1);                                    \
            _Pragma("unroll")                                                 \
            for (int mi = 0; mi < 4; ++mi)                                    \
                _Pragma("unroll")                                             \
                for (int nj = 0; nj < 4; ++nj)                                \
                    acc[mi][nj] = __builtin_amdgcn_mfma_f32_16x16x32_bf16(    \
                        af_[mi], bf_[nj], acc[mi][nj], 0, 0, 0);              \
            __builtin_amdgcn_s_setprio(0);                                    \
        }                                                                     \
    } while (0)

    f32x4 acc[4][4];
    #pragma unroll
    for (int mi = 0; mi < 4; ++mi)
        #pragma unroll
        for (int nj = 0; nj < 4; ++nj) acc[mi][nj] = (f32x4){0.f, 0.f, 0.f, 0.f};
    if (tid < 128) lds_g[tid] = 0.f;

    // iters: kt = it&7 (K-tile), tt = it>>3 (t-tile within quarter).
    // m97 pattern: stage -> vmcnt(0)+barrier -> compute -> barrier.
    #pragma unroll 1
    for (int it = 0; it < 32; ++it) {
        const int kt = it & 7, tt = it >> 3;
        STAGEA(kt);
        STAGEB(kt, tt);
        WAITVM0();
        BARRIER();
        COMPUTE();
        // K complete for this t-tile: sigmoid-weighted dump into lds_g.
        if (kt == 7) {
            const int tb = tq * 512 + tt * 128;
            float wt[4];
            #pragma unroll
            for (int nj = 0; nj < 4; ++nj) wt[nj] = wlast[tb + wn * 64 + nj * 16 + l15];
            #pragma unroll
            for (int mi = 0; mi < 4; ++mi)
                #pragma unroll
                for (int r = 0; r < 4; ++r) {
                    float v = 0.f;
                    #pragma unroll
                    for (int nj = 0; nj < 4; ++nj) {
                        const float e = __expf(-acc[mi][nj][r]);
                        v = fmaf(__builtin_amdgcn_rcpf(1.f + e), wt[nj], v);
                    }
                    v += __shfl_xor(v, 1);
                    v += __shfl_xor(v, 2);
                    v += __shfl_xor(v, 4);
                    v += __shfl_xor(v, 8);
                    if (l15 == 0) atomicAdd(&lds_g[wm * 64 + mi * 16 + quad * 4 + r], v);
                }
            #pragma unroll
            for (int mi = 0; mi < 4; ++mi)
                #pragma unroll
                for (int nj = 0; nj < 4; ++nj) acc[mi][nj] = (f32x4){0.f, 0.f, 0.f, 0.f};
        }
        BARRIER();   // WAR: all ds_reads done before next stage overwrites
    }
#undef STAGEA
#undef STAGEB
#undef COMPUTE

    __syncthreads();
    if (tid < 128) {
        const int srow = s0 + tid;
        if (srow < TM1) atomicAdd(&g0[b * TM1 + srow], lds_g[tid]);
    }
}

// --- r partials from bf16 xst (coalesced d-major) ------------------------
__global__ __launch_bounds__(256) void k_r(const ushort_t* __restrict__ xst,
                                           const float* __restrict__ g0,
                                           float* __restrict__ r0acc,
                                           float* __restrict__ sxacc, int b0) {
    const int sc = blockIdx.x;            // s-chunk of 64
    const int cc = blockIdx.y;
    const int b = b0 + cc;
    const ushort_t* xa = xst + (size_t)cc * BATCH_US;
    const float* g = g0 + b * TM1;
    const int d2 = threadIdx.x;           // owns d = 2*d2, 2*d2+1
    float a00 = 0.f, a01 = 0.f, a10 = 0.f, a11 = 0.f;
    const int send = (sc == 31) ? 63 : 64;   // exclude s = 2047
    for (int si = 0; si < send; ++si) {
        const int s = sc * 64 + si;
        const float gv = g[s];
        const uint_t pk = *(const uint_t*)&xa[(size_t)s * ND + d2 * 2];
        const float x0 = bf2f(pk & 0xFFFFu);
        const float x1 = bf2f(pk >> 16);
        a00 = fmaf(x0, gv, a00); a01 = fmaf(x1, gv, a01);
        a10 += x0; a11 += x1;
    }
    atomicAdd(&r0acc[b * ND + d2 * 2], a00);
    atomicAdd(&r0acc[b * ND + d2 * 2 + 1], a01);
    atomicAdd(&sxacc[b * ND + d2 * 2], a10);
    atomicAdd(&sxacc[b * ND + d2 * 2 + 1], a11);
}

// --- out[b,i] = sum_d W_PV[i,d] * r[b, i/256, d]  (fp32 out) -------------
__global__ __launch_bounds__(256) void k_out(const float* __restrict__ wpv,
                                             const float* __restrict__ r0acc,
                                             const float* __restrict__ sxacc,
                                             const float* __restrict__ wsum,
                                             float* __restrict__ out) {
    const int b = blockIdx.x;
    const int i0 = blockIdx.y * 256;
    __shared__ float rs[1024];
    const float wsv = *wsum;
    for (int i = threadIdx.x; i < ND; i += 256) {
        const float r0 = r0acc[b * ND + i];
        const float sx = sxacc[b * ND + i];
        rs[i] = r0;                        // head 0
        rs[ND + i] = fmaf(wsv, sx, -r0);   // head 1
    }
    __syncthreads();
    const int i = i0 + threadIdx.x;
    const float* wrow = wpv + (size_t)i * ND;
    const float* rh = rs + (i >> 8) * ND;
    float acc = 0.f;
    for (int dd = 0; dd < ND; dd += 4) {
        const float4 wv = *(const float4*)(wrow + dd);
        acc += wv.x * rh[dd] + wv.y * rh[dd + 1] + wv.z * rh[dd + 2] + wv.w * rh[dd + 3];
    }
    out[b * ND + i] = acc;
}

extern "C" void kernel_launch(void* const* d_in, const int* in_sizes, int n_in,
                              void* d_out, int out_size, void* d_ws, size_t ws_size,
                              hipStream_t stream) {
    (void)in_sizes; (void)n_in; (void)out_size;
    const float* xs   = (const float*)d_in[0];
    const float* wkq  = (const float*)d_in[1];
    const float* wpv  = (const float*)d_in[2];
    const float* wout = (const float*)d_in[3];
    const float* wlast = wout + (size_t)(NT - 1) * NT;  // W_out[-1]

    float* ws    = (float*)d_ws;
    float* g0    = ws + G0_OFF;
    float* r0acc = ws + R0_OFF;
    float* sxacc = ws + SX_OFF;
    float* wsum  = ws + WSUM_OFF;
    ushort_t* wkqT = (ushort_t*)(ws + WKQT_OFF);

    // Chunk batches: per batch needs 2 MB qdb + 2 MB xst of ws.
    const size_t ws_floats = ws_size / 4;
    size_t avail = (ws_floats > CHUNK_OFF) ? (ws_floats - CHUNK_OFF) : 0;
    int C = (int)(avail / BATCH_FLOATS);
    if (C > NB) C = NB;
    if (C < 1) C = 1;
    ushort_t* qdb = (ushort_t*)(ws + CHUNK_OFF);
    ushort_t* xst = (ushort_t*)(ws + CHUNK_OFF + (size_t)C * 524288ull);

    for (int b0 = 0; b0 < NB; b0 += C) {
        const int cb = (NB - b0 < C) ? (NB - b0) : C;
        k_cvt_xst<<<dim3(8, 8, cb), 256, 0, stream>>>(xs, xst, b0,
                                                      wkq, wkqT, wlast, wsum, ws);
        k_qd     <<<dim3(2, 8, cb),  512, 0, stream>>>(xst, wkqT, qdb);
        k_attn   <<<dim3(16, 4, cb), 256, 0, stream>>>(qdb, xst, wlast, g0, b0);
        k_r      <<<dim3(32, cb),    256, 0, stream>>>(xst, g0, r0acc, sxacc, b0);
    }
    k_out<<<dim3(NB, 2), 256, 0, stream>>>(wpv, r0acc, sxacc, wsum, (float*)d_out);
}